// Round 10
// baseline (176.507 us; speedup 1.0000x reference)
//
#include <hip/hip_runtime.h>
#include <hip/hip_bf16.h>

#define N_PIX 8192
#define C_DIM 128
#define HW 4096
// exp(dot/0.1) = exp2(dot * 14.42695...); fold sqrt of that into each vector.
#define PRESCALE 3.7982825f  // sqrt(log2(e)/0.1)
#define NUM_CLASSES 4

typedef __attribute__((ext_vector_type(8))) short short8;   // 8 x bf16 (4 VGPRs)
typedef __attribute__((ext_vector_type(4))) float float4v;  // 4 x f32 acc

// Fragment-linear layout (R7 win): ebfT[((T*4 + s)*64 + lane)*8 + j] = e[T*16 + lq][s*32 + quad*8 + j],
// lane = quad*16 + lq. Fragment load = base + lane*16B: one coalesced 1KB dwordx4.

// ---------------- Kernel 1: L2-normalize + prescale + bf16 cast into ebfT; zero pos/tot ----------------
__global__ __launch_bounds__(256) void normscale_kernel(const float* __restrict__ emb,
                                                        unsigned short* __restrict__ ebfT,
                                                        float* __restrict__ pz) {
    const int tid = threadIdx.x;
    const int p16 = tid & 15;   // pixel within tile (lq)
    const int g = tid >> 4;     // channel group 0..15 (8 channels each)
    const int n = blockIdx.x * 16 + p16;
    const int b = n >> 12;
    const int hw = n & (HW - 1);
    const float* base = emb + b * (C_DIM * HW) + hw;

    float v[8];
    float ss = 0.f;
#pragma unroll
    for (int i = 0; i < 8; ++i) {
        v[i] = base[(g * 8 + i) * HW];
        ss += v[i] * v[i];
    }
    ss += __shfl_xor(ss, 16, 64);
    ss += __shfl_xor(ss, 32, 64);
    __shared__ float red[4][16];
    const int wv = tid >> 6;
    if ((tid & 63) < 16) red[wv][p16] = ss;
    __syncthreads();
    float tot = red[0][p16] + red[1][p16] + red[2][p16] + red[3][p16];
    float inv = PRESCALE / fmaxf(sqrtf(tot), 1e-12f);

    unsigned short us[8];
#pragma unroll
    for (int i = 0; i < 8; ++i) {
        __hip_bfloat16 h = __float2bfloat16(v[i] * inv);
        us[i] = *reinterpret_cast<unsigned short*>(&h);
    }
    const int s = g >> 2, quad = g & 3;
    unsigned short* dst = ebfT + (((blockIdx.x * 4 + s) * 64 + quad * 16 + p16) << 3);
    *reinterpret_cast<short8*>(dst) = *reinterpret_cast<short8*>(us);

    if (blockIdx.x < 64) pz[blockIdx.x * 256 + tid] = 0.f;
}

// ---------------- Kernel 2: symmetric fused S = e e^T, exp2, row+col sums ----------------
// Grid (64, 32): bi = I-panel (128 rows), d = blockIdx.y+1 in 1..32; jp = (bi+d)%64.
// d=1..31 covers each unordered off-diag panel pair once ({a,b}: one of the two
// direction-diffs is in 1..31); d=32 double-covers -> bi>=32 culled.
// Phase 1 (all blocks): off-diag pair, single path, no masking, no in-loop flush:
//   col-side partials accumulate in registers colT_r[8]/colP_r[8] (R9 lesson: per-tile
//   global atomic flush = 2.6M lane-atomics ~ 34us of L2 atomic throughput, ate the
//   symmetry win; now 1 atomic/col/block via end-of-kernel LDS combine = 0.8M total).
// Phase 2 (d==1 only): diagonal panel, separate sequential loop, self-mask, row-side only.
// Lessons: (256,4) not (256,8) [R3]; plain cached loads [R5]; macros + constant-indexed
// arrays only [R6]; ONE code path in any tile loop [R8]; LDS only outside the loop.
__global__ __launch_bounds__(256, 4) void pairwise_kernel(const unsigned short* __restrict__ ebfT,
                                                          const int* __restrict__ lab,
                                                          float* __restrict__ pos,
                                                          float* __restrict__ tot) {
    const int bi = blockIdx.x;
    const int d = blockIdx.y + 1;          // 1..32
    if (d == 32 && bi >= 32) return;       // wrap double-cover cull (block-uniform)
    const int jp = (bi + d) & 63;
    const int Ipanel = bi << 7;
    const int Jpanel = jp << 7;

    const int wave = threadIdx.x >> 6;
    const int lane = threadIdx.x & 63;
    const int quad = lane >> 4;
    const int lq = lane & 15;

    const int I0 = Ipanel + wave * 32;

    // A fragments: tiles (I0>>4), (I0>>4)+1 — coalesced lane*16B loads.
    short8 afrag[2][4];
#pragma unroll
    for (int a = 0; a < 2; ++a) {
        const unsigned short* ab = ebfT + ((((I0 >> 4) + a) * 4) * 64 + lane) * 8;
#pragma unroll
        for (int s = 0; s < 4; ++s)
            afrag[a][s] = *reinterpret_cast<const short8*>(ab + s * 512);
    }
    int lab_row[2][4];
#pragma unroll
    for (int a = 0; a < 2; ++a)
#pragma unroll
        for (int r = 0; r < 4; ++r) lab_row[a][r] = lab[I0 + a * 16 + quad * 4 + r];

    float tacc[2][4] = {};
    float pacc[2][4] = {};
    float colT_r[8] = {};
    float colP_r[8] = {};

    // ---- Phase 1: off-diagonal panel pair (no masking, row + col side, no flush) ----
    {
        const unsigned short* bbase = ebfT + ((Jpanel >> 4) * 4 * 64 + lane) * 8;
#pragma unroll
        for (int t = 0; t < 8; ++t) {
            const int lab_col = lab[Jpanel + t * 16 + lq];
            const unsigned short* bt = bbase + t * 2048;
            short8 bfrag[4];
#pragma unroll
            for (int s = 0; s < 4; ++s)
                bfrag[s] = *reinterpret_cast<const short8*>(bt + s * 512);

            float4v acc0 = {0.f, 0.f, 0.f, 0.f};
            float4v acc1 = {0.f, 0.f, 0.f, 0.f};
#pragma unroll
            for (int s = 0; s < 4; ++s) {
                acc0 = __builtin_amdgcn_mfma_f32_16x16x32_bf16(afrag[0][s], bfrag[s], acc0, 0, 0, 0);
                acc1 = __builtin_amdgcn_mfma_f32_16x16x32_bf16(afrag[1][s], bfrag[s], acc1, 0, 0, 0);
            }

#pragma unroll
            for (int r = 0; r < 4; ++r) {
                float ex = __builtin_amdgcn_exp2f(acc0[r]);
                tacc[0][r] += ex;
                float pxe = (lab_row[0][r] == lab_col) ? ex : 0.f;
                pacc[0][r] += pxe;
                colT_r[t] += ex;
                colP_r[t] += pxe;
            }
#pragma unroll
            for (int r = 0; r < 4; ++r) {
                float ex = __builtin_amdgcn_exp2f(acc1[r]);
                tacc[1][r] += ex;
                float pxe = (lab_row[1][r] == lab_col) ? ex : 0.f;
                pacc[1][r] += pxe;
                colT_r[t] += ex;
                colP_r[t] += pxe;
            }
        }
    }

    // ---- Phase 2 (d==1 blocks only): diagonal panel bi, self-masked, row-side only ----
#define EPILOGUE(A, ACC, MASKED)                                            \
    {                                                                       \
        _Pragma("unroll") for (int r = 0; r < 4; ++r) {                     \
            float ex = __builtin_amdgcn_exp2f(ACC[r]);                      \
            if (MASKED) ex = (lq == quad * 4 + r) ? 0.f : ex;               \
            tacc[A][r] += ex;                                               \
            pacc[A][r] += (lab_row[A][r] == lab_col) ? ex : 0.f;            \
        }                                                                   \
    }
    if (d == 1) {
        const unsigned short* bbase = ebfT + ((Ipanel >> 4) * 4 * 64 + lane) * 8;
        for (int t = 0; t < 8; ++t) {
            const int J = Ipanel + t * 16;
            const int lab_col = lab[J + lq];
            const unsigned short* bt = bbase + t * 2048;
            short8 bfrag[4];
#pragma unroll
            for (int s = 0; s < 4; ++s)
                bfrag[s] = *reinterpret_cast<const short8*>(bt + s * 512);

            float4v acc0 = {0.f, 0.f, 0.f, 0.f};
            float4v acc1 = {0.f, 0.f, 0.f, 0.f};
#pragma unroll
            for (int s = 0; s < 4; ++s) {
                acc0 = __builtin_amdgcn_mfma_f32_16x16x32_bf16(afrag[0][s], bfrag[s], acc0, 0, 0, 0);
                acc1 = __builtin_amdgcn_mfma_f32_16x16x32_bf16(afrag[1][s], bfrag[s], acc1, 0, 0, 0);
            }
            if (J == I0) EPILOGUE(0, acc0, true) else EPILOGUE(0, acc0, false);
            if (J == I0 + 16) EPILOGUE(1, acc1, true) else EPILOGUE(1, acc1, false);
        }
    }
#undef EPILOGUE

    // ---- Row-side flush (covers phase 1 + phase 2): one atomic per row per block ----
#pragma unroll
    for (int a = 0; a < 2; ++a) {
#pragma unroll
        for (int r = 0; r < 4; ++r) {
            float t = tacc[a][r], p = pacc[a][r];
#pragma unroll
            for (int off = 1; off < 16; off <<= 1) {
                t += __shfl_xor(t, off, 64);
                p += __shfl_xor(p, off, 64);
            }
            if (lq == 0) {
                const int row = I0 + a * 16 + quad * 4 + r;
                atomicAdd(&tot[row], t);
                atomicAdd(&pos[row], p);
            }
        }
    }

    // ---- Col-side flush: wave-reduce, LDS combine, one atomic per col per block ----
    __shared__ float clsT[4][128];
    __shared__ float clsP[4][128];
#pragma unroll
    for (int t = 0; t < 8; ++t) {
        float ct = colT_r[t], cp = colP_r[t];
        ct += __shfl_xor(ct, 16, 64);
        ct += __shfl_xor(ct, 32, 64);
        cp += __shfl_xor(cp, 16, 64);
        cp += __shfl_xor(cp, 32, 64);
        if (quad == 0) {
            clsT[wave][t * 16 + lq] = ct;
            clsP[wave][t * 16 + lq] = cp;
        }
    }
    __syncthreads();
    if (threadIdx.x < 128) {
        const int c = threadIdx.x;
        atomicAdd(&tot[Jpanel + c], clsT[0][c] + clsT[1][c] + clsT[2][c] + clsT[3][c]);
    } else {
        const int c = threadIdx.x - 128;
        atomicAdd(&pos[Jpanel + c], clsP[0][c] + clsP[1][c] + clsP[2][c] + clsP[3][c]);
    }
}

// ---------------- Kernel 3: row losses + per-class mean of means ----------------
__global__ __launch_bounds__(1024) void finalize_kernel(const float* __restrict__ pos,
                                                        const float* __restrict__ tot,
                                                        const int* __restrict__ lab,
                                                        float* __restrict__ out) {
    const int tid = threadIdx.x;
    float ls[NUM_CLASSES] = {0.f, 0.f, 0.f, 0.f};
    float lc[NUM_CLASSES] = {0.f, 0.f, 0.f, 0.f};
#pragma unroll
    for (int it = 0; it < N_PIX / 1024; ++it) {
        const int n = it * 1024 + tid;
        float rl = logf(tot[n] + 1e-6f) - logf(pos[n]);
        int c = lab[n];
#pragma unroll
        for (int k = 0; k < NUM_CLASSES; ++k) {
            if (c == k) {
                ls[k] += rl;
                lc[k] += 1.f;
            }
        }
    }
#pragma unroll
    for (int off = 1; off < 64; off <<= 1) {
#pragma unroll
        for (int k = 0; k < NUM_CLASSES; ++k) {
            ls[k] += __shfl_xor(ls[k], off, 64);
            lc[k] += __shfl_xor(lc[k], off, 64);
        }
    }
    __shared__ float ssum[16][NUM_CLASSES];
    __shared__ float scnt[16][NUM_CLASSES];
    const int wid = tid >> 6;
    if ((tid & 63) == 0) {
#pragma unroll
        for (int k = 0; k < NUM_CLASSES; ++k) {
            ssum[wid][k] = ls[k];
            scnt[wid][k] = lc[k];
        }
    }
    __syncthreads();
    if (tid == 0) {
        float acc = 0.f;
        int present = 0;
        for (int k = 0; k < NUM_CLASSES; ++k) {
            float s = 0.f, c = 0.f;
            for (int w = 0; w < 16; ++w) {
                s += ssum[w][k];
                c += scnt[w][k];
            }
            if (c > 0.f) {
                acc += s / c;
                present++;
            }
        }
        out[0] = acc / (float)(present > 0 ? present : 1);
    }
}

extern "C" void kernel_launch(void* const* d_in, const int* in_sizes, int n_in,
                              void* d_out, int out_size, void* d_ws, size_t ws_size,
                              hipStream_t stream) {
    const float* emb = (const float*)d_in[0];  // [2,128,64,64] fp32
    const int* lab = (const int*)d_in[1];      // [2,64,64] int32
    float* out = (float*)d_out;

    unsigned short* ebfT = (unsigned short*)d_ws;            // [512 tiles][4][64][8] bf16 = 2 MiB
    float* pos = (float*)((char*)d_ws + N_PIX * C_DIM * 2);  // [8192] f32
    float* tot = pos + N_PIX;                                // [8192] f32 (contiguous)

    normscale_kernel<<<N_PIX / 16, 256, 0, stream>>>(emb, ebfT, pos);

    dim3 grid(64, 32);  // symmetric panel-pair cover
    pairwise_kernel<<<grid, 256, 0, stream>>>(ebfT, lab, pos, tot);

    finalize_kernel<<<1, 1024, 0, stream>>>(pos, tot, lab, out);
}

// Round 11
// 151.578 us; speedup vs baseline: 1.1645x; 1.1645x over previous
//
#include <hip/hip_runtime.h>
#include <hip/hip_bf16.h>

#define N_PIX 8192
#define C_DIM 128
#define HW 4096
// exp(dot/0.1) = exp2(dot * 14.42695...); fold sqrt of that into each vector.
#define PRESCALE 3.7982825f  // sqrt(log2(e)/0.1)
#define NUM_CLASSES 4

typedef __attribute__((ext_vector_type(8))) short short8;   // 8 x bf16 (4 VGPRs)
typedef __attribute__((ext_vector_type(4))) float float4v;  // 4 x f32 acc

// Fragment-linear layout (R7 win): ebfT[((T*4 + s)*64 + lane)*8 + j] = e[T*16 + lq][s*32 + quad*8 + j],
// lane = quad*16 + lq. Fragment load = base + lane*16B: one coalesced 1KB dwordx4.

// ---------------- Kernel 1: L2-normalize + prescale + bf16 cast into ebfT; zero pos/tot ----------------
__global__ __launch_bounds__(256) void normscale_kernel(const float* __restrict__ emb,
                                                        unsigned short* __restrict__ ebfT,
                                                        float* __restrict__ pz) {
    const int tid = threadIdx.x;
    const int p16 = tid & 15;   // pixel within tile (lq)
    const int g = tid >> 4;     // channel group 0..15 (8 channels each)
    const int n = blockIdx.x * 16 + p16;
    const int b = n >> 12;
    const int hw = n & (HW - 1);
    const float* base = emb + b * (C_DIM * HW) + hw;

    float v[8];
    float ss = 0.f;
#pragma unroll
    for (int i = 0; i < 8; ++i) {
        v[i] = base[(g * 8 + i) * HW];
        ss += v[i] * v[i];
    }
    ss += __shfl_xor(ss, 16, 64);
    ss += __shfl_xor(ss, 32, 64);
    __shared__ float red[4][16];
    const int wv = tid >> 6;
    if ((tid & 63) < 16) red[wv][p16] = ss;
    __syncthreads();
    float tot = red[0][p16] + red[1][p16] + red[2][p16] + red[3][p16];
    float inv = PRESCALE / fmaxf(sqrtf(tot), 1e-12f);

    unsigned short us[8];
#pragma unroll
    for (int i = 0; i < 8; ++i) {
        __hip_bfloat16 h = __float2bfloat16(v[i] * inv);
        us[i] = *reinterpret_cast<unsigned short*>(&h);
    }
    const int s = g >> 2, quad = g & 3;
    unsigned short* dst = ebfT + (((blockIdx.x * 4 + s) * 64 + quad * 16 + p16) << 3);
    *reinterpret_cast<short8*>(dst) = *reinterpret_cast<short8*>(us);

    if (blockIdx.x < 64) pz[blockIdx.x * 256 + tid] = 0.f;
}

// ---------------- Kernel 2: symmetric fused S = e e^T, exp2, row+col sums ----------------
// Grid (64, 32): bi = I-panel (128 rows), d = blockIdx.y+1 in 1..32; jp = (bi+d)%64.
// d=1..31 covers each unordered off-diag panel pair once; d=32 double-covers -> bi>=32 culled.
// Phase 1 (all blocks): off-diag pair, single path, no masking. Col-side partials are
//   wave-reduced per tile and written to a wave-private LDS slot (plain ds_write,
//   SHORT liveness — R10 lesson: register arrays live across phase 2 get demoted to
//   scratch; R9 lesson: per-tile GLOBAL atomic flush = 2.1M L2 atomics ~ 34us).
//   End-of-kernel combine: one global atomic per col per block (0.8M total, R7 level).
// Phase 2 (d==1 only): diagonal panel, separate sequential loop, self-mask, row-side only.
// Lessons: (256,4) not (256,8) [R3]; plain cached loads [R5]; macros + constant-indexed
// arrays only, no lambdas [R6]; ONE code path in any tile loop [R8].
__global__ __launch_bounds__(256, 4) void pairwise_kernel(const unsigned short* __restrict__ ebfT,
                                                          const int* __restrict__ lab,
                                                          float* __restrict__ pos,
                                                          float* __restrict__ tot) {
    const int bi = blockIdx.x;
    const int d = blockIdx.y + 1;          // 1..32
    if (d == 32 && bi >= 32) return;       // wrap double-cover cull (block-uniform)
    const int jp = (bi + d) & 63;
    const int Ipanel = bi << 7;
    const int Jpanel = jp << 7;

    __shared__ float clsT[4][128];
    __shared__ float clsP[4][128];

    const int wave = threadIdx.x >> 6;
    const int lane = threadIdx.x & 63;
    const int quad = lane >> 4;
    const int lq = lane & 15;

    const int I0 = Ipanel + wave * 32;

    // A fragments: tiles (I0>>4), (I0>>4)+1 — coalesced lane*16B loads.
    short8 afrag[2][4];
#pragma unroll
    for (int a = 0; a < 2; ++a) {
        const unsigned short* ab = ebfT + ((((I0 >> 4) + a) * 4) * 64 + lane) * 8;
#pragma unroll
        for (int s = 0; s < 4; ++s)
            afrag[a][s] = *reinterpret_cast<const short8*>(ab + s * 512);
    }
    int lab_row[2][4];
#pragma unroll
    for (int a = 0; a < 2; ++a)
#pragma unroll
        for (int r = 0; r < 4; ++r) lab_row[a][r] = lab[I0 + a * 16 + quad * 4 + r];

    float tacc[2][4] = {};
    float pacc[2][4] = {};

    // ---- Phase 1: off-diagonal panel pair (no masking, row + col side) ----
    {
        const unsigned short* bbase = ebfT + ((Jpanel >> 4) * 4 * 64 + lane) * 8;
#pragma unroll
        for (int t = 0; t < 8; ++t) {
            const int lab_col = lab[Jpanel + t * 16 + lq];
            const unsigned short* bt = bbase + t * 2048;
            short8 bfrag[4];
#pragma unroll
            for (int s = 0; s < 4; ++s)
                bfrag[s] = *reinterpret_cast<const short8*>(bt + s * 512);

            float4v acc0 = {0.f, 0.f, 0.f, 0.f};
            float4v acc1 = {0.f, 0.f, 0.f, 0.f};
#pragma unroll
            for (int s = 0; s < 4; ++s) {
                acc0 = __builtin_amdgcn_mfma_f32_16x16x32_bf16(afrag[0][s], bfrag[s], acc0, 0, 0, 0);
                acc1 = __builtin_amdgcn_mfma_f32_16x16x32_bf16(afrag[1][s], bfrag[s], acc1, 0, 0, 0);
            }

            float colTs = 0.f, colPs = 0.f;
#pragma unroll
            for (int r = 0; r < 4; ++r) {
                float ex = __builtin_amdgcn_exp2f(acc0[r]);
                tacc[0][r] += ex;
                float pxe = (lab_row[0][r] == lab_col) ? ex : 0.f;
                pacc[0][r] += pxe;
                colTs += ex;
                colPs += pxe;
            }
#pragma unroll
            for (int r = 0; r < 4; ++r) {
                float ex = __builtin_amdgcn_exp2f(acc1[r]);
                tacc[1][r] += ex;
                float pxe = (lab_row[1][r] == lab_col) ? ex : 0.f;
                pacc[1][r] += pxe;
                colTs += ex;
                colPs += pxe;
            }
            // col-side: this wave's 32-row partial for col = Jpanel + t*16 + lq,
            // reduced over quads and parked in the wave-private LDS slot (no atomics).
            colTs += __shfl_xor(colTs, 16, 64);
            colTs += __shfl_xor(colTs, 32, 64);
            colPs += __shfl_xor(colPs, 16, 64);
            colPs += __shfl_xor(colPs, 32, 64);
            if (quad == 0) {
                clsT[wave][t * 16 + lq] = colTs;
                clsP[wave][t * 16 + lq] = colPs;
            }
        }
    }

    // ---- Phase 2 (d==1 blocks only): diagonal panel bi, self-masked, row-side only ----
#define EPILOGUE(A, ACC, MASKED)                                            \
    {                                                                       \
        _Pragma("unroll") for (int r = 0; r < 4; ++r) {                     \
            float ex = __builtin_amdgcn_exp2f(ACC[r]);                      \
            if (MASKED) ex = (lq == quad * 4 + r) ? 0.f : ex;               \
            tacc[A][r] += ex;                                               \
            pacc[A][r] += (lab_row[A][r] == lab_col) ? ex : 0.f;            \
        }                                                                   \
    }
    if (d == 1) {
        const unsigned short* bbase = ebfT + ((Ipanel >> 4) * 4 * 64 + lane) * 8;
        for (int t = 0; t < 8; ++t) {
            const int J = Ipanel + t * 16;
            const int lab_col = lab[J + lq];
            const unsigned short* bt = bbase + t * 2048;
            short8 bfrag[4];
#pragma unroll
            for (int s = 0; s < 4; ++s)
                bfrag[s] = *reinterpret_cast<const short8*>(bt + s * 512);

            float4v acc0 = {0.f, 0.f, 0.f, 0.f};
            float4v acc1 = {0.f, 0.f, 0.f, 0.f};
#pragma unroll
            for (int s = 0; s < 4; ++s) {
                acc0 = __builtin_amdgcn_mfma_f32_16x16x32_bf16(afrag[0][s], bfrag[s], acc0, 0, 0, 0);
                acc1 = __builtin_amdgcn_mfma_f32_16x16x32_bf16(afrag[1][s], bfrag[s], acc1, 0, 0, 0);
            }
            if (J == I0) EPILOGUE(0, acc0, true) else EPILOGUE(0, acc0, false);
            if (J == I0 + 16) EPILOGUE(1, acc1, true) else EPILOGUE(1, acc1, false);
        }
    }
#undef EPILOGUE

    // ---- Row-side flush (covers phase 1 + phase 2): one atomic per row per block ----
#pragma unroll
    for (int a = 0; a < 2; ++a) {
#pragma unroll
        for (int r = 0; r < 4; ++r) {
            float t = tacc[a][r], p = pacc[a][r];
#pragma unroll
            for (int off = 1; off < 16; off <<= 1) {
                t += __shfl_xor(t, off, 64);
                p += __shfl_xor(p, off, 64);
            }
            if (lq == 0) {
                const int row = I0 + a * 16 + quad * 4 + r;
                atomicAdd(&tot[row], t);
                atomicAdd(&pos[row], p);
            }
        }
    }

    // ---- Col-side flush: combine 4 waves' LDS slots, one atomic per col per block ----
    __syncthreads();
    if (threadIdx.x < 128) {
        const int c = threadIdx.x;
        atomicAdd(&tot[Jpanel + c], clsT[0][c] + clsT[1][c] + clsT[2][c] + clsT[3][c]);
    } else {
        const int c = threadIdx.x - 128;
        atomicAdd(&pos[Jpanel + c], clsP[0][c] + clsP[1][c] + clsP[2][c] + clsP[3][c]);
    }
}

// ---------------- Kernel 3: row losses + per-class mean of means ----------------
__global__ __launch_bounds__(1024) void finalize_kernel(const float* __restrict__ pos,
                                                        const float* __restrict__ tot,
                                                        const int* __restrict__ lab,
                                                        float* __restrict__ out) {
    const int tid = threadIdx.x;
    float ls[NUM_CLASSES] = {0.f, 0.f, 0.f, 0.f};
    float lc[NUM_CLASSES] = {0.f, 0.f, 0.f, 0.f};
#pragma unroll
    for (int it = 0; it < N_PIX / 1024; ++it) {
        const int n = it * 1024 + tid;
        float rl = logf(tot[n] + 1e-6f) - logf(pos[n]);
        int c = lab[n];
#pragma unroll
        for (int k = 0; k < NUM_CLASSES; ++k) {
            if (c == k) {
                ls[k] += rl;
                lc[k] += 1.f;
            }
        }
    }
#pragma unroll
    for (int off = 1; off < 64; off <<= 1) {
#pragma unroll
        for (int k = 0; k < NUM_CLASSES; ++k) {
            ls[k] += __shfl_xor(ls[k], off, 64);
            lc[k] += __shfl_xor(lc[k], off, 64);
        }
    }
    __shared__ float ssum[16][NUM_CLASSES];
    __shared__ float scnt[16][NUM_CLASSES];
    const int wid = tid >> 6;
    if ((tid & 63) == 0) {
#pragma unroll
        for (int k = 0; k < NUM_CLASSES; ++k) {
            ssum[wid][k] = ls[k];
            scnt[wid][k] = lc[k];
        }
    }
    __syncthreads();
    if (tid == 0) {
        float acc = 0.f;
        int present = 0;
        for (int k = 0; k < NUM_CLASSES; ++k) {
            float s = 0.f, c = 0.f;
            for (int w = 0; w < 16; ++w) {
                s += ssum[w][k];
                c += scnt[w][k];
            }
            if (c > 0.f) {
                acc += s / c;
                present++;
            }
        }
        out[0] = acc / (float)(present > 0 ? present : 1);
    }
}

extern "C" void kernel_launch(void* const* d_in, const int* in_sizes, int n_in,
                              void* d_out, int out_size, void* d_ws, size_t ws_size,
                              hipStream_t stream) {
    const float* emb = (const float*)d_in[0];  // [2,128,64,64] fp32
    const int* lab = (const int*)d_in[1];      // [2,64,64] int32
    float* out = (float*)d_out;

    unsigned short* ebfT = (unsigned short*)d_ws;            // [512 tiles][4][64][8] bf16 = 2 MiB
    float* pos = (float*)((char*)d_ws + N_PIX * C_DIM * 2);  // [8192] f32
    float* tot = pos + N_PIX;                                // [8192] f32 (contiguous)

    normscale_kernel<<<N_PIX / 16, 256, 0, stream>>>(emb, ebfT, pos);

    dim3 grid(64, 32);  // symmetric panel-pair cover
    pairwise_kernel<<<grid, 256, 0, stream>>>(ebfT, lab, pos, tot);

    finalize_kernel<<<1, 1024, 0, stream>>>(pos, tot, lab, out);
}

// Round 12
// 148.654 us; speedup vs baseline: 1.1874x; 1.0197x over previous
//
#include <hip/hip_runtime.h>
#include <hip/hip_bf16.h>

#define N_PIX 8192
#define C_DIM 128
#define HW 4096
// exp(dot/0.1) = exp2(dot * 14.42695...); fold sqrt of that into each vector.
#define PRESCALE 3.7982825f  // sqrt(log2(e)/0.1)
#define NUM_CLASSES 4

typedef __attribute__((ext_vector_type(8))) short short8;   // 8 x bf16 (4 VGPRs)
typedef __attribute__((ext_vector_type(4))) float float4v;  // 4 x f32 acc

// Fragment-linear layout (R7 win): ebfT[((T*4 + s)*64 + lane)*8 + j] = e[T*16 + lq][s*32 + quad*8 + j],
// lane = quad*16 + lq. Fragment load = base + lane*16B: one coalesced 1KB dwordx4.

// ---------------- Kernel 1: L2-normalize + prescale + bf16 cast into ebfT; zero pos/tot ----------------
__global__ __launch_bounds__(256) void normscale_kernel(const float* __restrict__ emb,
                                                        unsigned short* __restrict__ ebfT,
                                                        float* __restrict__ pz) {
    const int tid = threadIdx.x;
    const int p16 = tid & 15;   // pixel within tile (lq)
    const int g = tid >> 4;     // channel group 0..15 (8 channels each)
    const int n = blockIdx.x * 16 + p16;
    const int b = n >> 12;
    const int hw = n & (HW - 1);
    const float* base = emb + b * (C_DIM * HW) + hw;

    float v[8];
    float ss = 0.f;
#pragma unroll
    for (int i = 0; i < 8; ++i) {
        v[i] = base[(g * 8 + i) * HW];
        ss += v[i] * v[i];
    }
    ss += __shfl_xor(ss, 16, 64);
    ss += __shfl_xor(ss, 32, 64);
    __shared__ float red[4][16];
    const int wv = tid >> 6;
    if ((tid & 63) < 16) red[wv][p16] = ss;
    __syncthreads();
    float tot = red[0][p16] + red[1][p16] + red[2][p16] + red[3][p16];
    float inv = PRESCALE / fmaxf(sqrtf(tot), 1e-12f);

    unsigned short us[8];
#pragma unroll
    for (int i = 0; i < 8; ++i) {
        __hip_bfloat16 h = __float2bfloat16(v[i] * inv);
        us[i] = *reinterpret_cast<unsigned short*>(&h);
    }
    const int s = g >> 2, quad = g & 3;
    unsigned short* dst = ebfT + (((blockIdx.x * 4 + s) * 64 + quad * 16 + p16) << 3);
    *reinterpret_cast<short8*>(dst) = *reinterpret_cast<short8*>(us);

    if (blockIdx.x < 64) pz[blockIdx.x * 256 + tid] = 0.f;
}

// ---------------- Kernel 2: symmetric fused S = e e^T, exp2, row+col sums ----------------
// Grid (64, 32): bi = I-panel (128 rows), d = blockIdx.y+1 in 1..32; jp = (bi+d)%64.
// d=1..31 covers each unordered off-diag panel pair once; d=32 double-covers -> bi>=32 culled.
// Phase 1 (all blocks): off-diag pair, single path, no masking. Col-side partials are
//   quad-reduced per tile and written via plain global stores to a (slot, wave)-private
//   scratch region; colreduce_kernel sums the slots afterwards. NO LDS in this kernel.
// Phase 2 (d==1 only): diagonal panel, separate sequential loop, self-mask, row-side only.
// HARD-WON toolchain rules (scratch-demotion signature = VGPR 64 + WRITE >100MB):
//   R3: (256,8) spills -> keep (256,4).    R5: no global_load_lds here (traffic blowup).
//   R6: no lambdas / address-taken arrays. R8/R11 vs R9: ANY in-tile-loop LDS access
//   demotes; in-loop GLOBAL ops are fine.  R9: in-loop global ATOMICS = 2.1M L2 RMWs
//   (~15-20us) -> plain stores instead.    R10: no register arrays across phases.
__global__ __launch_bounds__(256, 4) void pairwise_kernel(const unsigned short* __restrict__ ebfT,
                                                          const int* __restrict__ lab,
                                                          float* __restrict__ pos,
                                                          float* __restrict__ tot,
                                                          float* __restrict__ colscr) {
    const int bi = blockIdx.x;
    const int d = blockIdx.y + 1;          // 1..32
    if (d == 32 && bi >= 32) return;       // wrap double-cover cull (block-uniform)
    const int jp = (bi + d) & 63;
    const int Ipanel = bi << 7;
    const int Jpanel = jp << 7;

    const int wave = threadIdx.x >> 6;
    const int lane = threadIdx.x & 63;
    const int quad = lane >> 4;
    const int lq = lane & 15;

    const int I0 = Ipanel + wave * 32;
    // (slot, wave)-private scratch: colscr[((sid*4 + wave)*256) + {0|128} + col]
    float* scrw = colscr + (((((d - 1) << 6) + bi) << 2) + wave) * 256;

    // A fragments: tiles (I0>>4), (I0>>4)+1 — coalesced lane*16B loads.
    short8 afrag[2][4];
#pragma unroll
    for (int a = 0; a < 2; ++a) {
        const unsigned short* ab = ebfT + ((((I0 >> 4) + a) * 4) * 64 + lane) * 8;
#pragma unroll
        for (int s = 0; s < 4; ++s)
            afrag[a][s] = *reinterpret_cast<const short8*>(ab + s * 512);
    }
    int lab_row[2][4];
#pragma unroll
    for (int a = 0; a < 2; ++a)
#pragma unroll
        for (int r = 0; r < 4; ++r) lab_row[a][r] = lab[I0 + a * 16 + quad * 4 + r];

    float tacc[2][4] = {};
    float pacc[2][4] = {};

    // ---- Phase 1: off-diagonal panel pair (no masking, row + col side) ----
    {
        const unsigned short* bbase = ebfT + ((Jpanel >> 4) * 4 * 64 + lane) * 8;
#pragma unroll
        for (int t = 0; t < 8; ++t) {
            const int lab_col = lab[Jpanel + t * 16 + lq];
            const unsigned short* bt = bbase + t * 2048;
            short8 bfrag[4];
#pragma unroll
            for (int s = 0; s < 4; ++s)
                bfrag[s] = *reinterpret_cast<const short8*>(bt + s * 512);

            float4v acc0 = {0.f, 0.f, 0.f, 0.f};
            float4v acc1 = {0.f, 0.f, 0.f, 0.f};
#pragma unroll
            for (int s = 0; s < 4; ++s) {
                acc0 = __builtin_amdgcn_mfma_f32_16x16x32_bf16(afrag[0][s], bfrag[s], acc0, 0, 0, 0);
                acc1 = __builtin_amdgcn_mfma_f32_16x16x32_bf16(afrag[1][s], bfrag[s], acc1, 0, 0, 0);
            }

            float colTs = 0.f, colPs = 0.f;
#pragma unroll
            for (int r = 0; r < 4; ++r) {
                float ex = __builtin_amdgcn_exp2f(acc0[r]);
                tacc[0][r] += ex;
                float pxe = (lab_row[0][r] == lab_col) ? ex : 0.f;
                pacc[0][r] += pxe;
                colTs += ex;
                colPs += pxe;
            }
#pragma unroll
            for (int r = 0; r < 4; ++r) {
                float ex = __builtin_amdgcn_exp2f(acc1[r]);
                tacc[1][r] += ex;
                float pxe = (lab_row[1][r] == lab_col) ? ex : 0.f;
                pacc[1][r] += pxe;
                colTs += ex;
                colPs += pxe;
            }
            // col-side: reduce over quads; quad 0 stores the wave's 32-row partial.
            colTs += __shfl_xor(colTs, 16, 64);
            colTs += __shfl_xor(colTs, 32, 64);
            colPs += __shfl_xor(colPs, 16, 64);
            colPs += __shfl_xor(colPs, 32, 64);
            if (quad == 0) {
                scrw[t * 16 + lq] = colTs;
                scrw[128 + t * 16 + lq] = colPs;
            }
        }
    }

    // ---- Phase 2 (d==1 blocks only): diagonal panel bi, self-masked, row-side only ----
#define EPILOGUE(A, ACC, MASKED)                                            \
    {                                                                       \
        _Pragma("unroll") for (int r = 0; r < 4; ++r) {                     \
            float ex = __builtin_amdgcn_exp2f(ACC[r]);                      \
            if (MASKED) ex = (lq == quad * 4 + r) ? 0.f : ex;               \
            tacc[A][r] += ex;                                               \
            pacc[A][r] += (lab_row[A][r] == lab_col) ? ex : 0.f;            \
        }                                                                   \
    }
    if (d == 1) {
        const unsigned short* bbase = ebfT + ((Ipanel >> 4) * 4 * 64 + lane) * 8;
        for (int t = 0; t < 8; ++t) {
            const int J = Ipanel + t * 16;
            const int lab_col = lab[J + lq];
            const unsigned short* bt = bbase + t * 2048;
            short8 bfrag[4];
#pragma unroll
            for (int s = 0; s < 4; ++s)
                bfrag[s] = *reinterpret_cast<const short8*>(bt + s * 512);

            float4v acc0 = {0.f, 0.f, 0.f, 0.f};
            float4v acc1 = {0.f, 0.f, 0.f, 0.f};
#pragma unroll
            for (int s = 0; s < 4; ++s) {
                acc0 = __builtin_amdgcn_mfma_f32_16x16x32_bf16(afrag[0][s], bfrag[s], acc0, 0, 0, 0);
                acc1 = __builtin_amdgcn_mfma_f32_16x16x32_bf16(afrag[1][s], bfrag[s], acc1, 0, 0, 0);
            }
            if (J == I0) EPILOGUE(0, acc0, true) else EPILOGUE(0, acc0, false);
            if (J == I0 + 16) EPILOGUE(1, acc1, true) else EPILOGUE(1, acc1, false);
        }
    }
#undef EPILOGUE

    // ---- Row-side flush (covers phase 1 + phase 2): one atomic per row per block ----
#pragma unroll
    for (int a = 0; a < 2; ++a) {
#pragma unroll
        for (int r = 0; r < 4; ++r) {
            float t = tacc[a][r], p = pacc[a][r];
#pragma unroll
            for (int off = 1; off < 16; off <<= 1) {
                t += __shfl_xor(t, off, 64);
                p += __shfl_xor(p, off, 64);
            }
            if (lq == 0) {
                const int row = I0 + a * 16 + quad * 4 + r;
                atomicAdd(&tot[row], t);
                atomicAdd(&pos[row], p);
            }
        }
    }
}

// ---------------- Kernel 2b: col-side reduce of scratch slots into tot/pos ----------------
// One thread per col c. Sums the 4 wave-quarters of every valid slot (bi=(jp-d)%64, d).
__global__ __launch_bounds__(256) void colreduce_kernel(const float* __restrict__ colscr,
                                                        float* __restrict__ pos,
                                                        float* __restrict__ tot) {
    const int c = blockIdx.x * 256 + threadIdx.x;  // 0..8191
    const int jpp = c >> 7;
    const int cc = c & 127;
    float st = 0.f, sp = 0.f;
    for (int d = 1; d <= 32; ++d) {
        const int bi = (jpp - d + 64) & 63;
        if (d == 32 && bi >= 32) continue;
        const float* s0 = colscr + ((((d - 1) << 6) + bi) << 2) * 256;
        st += s0[cc] + s0[256 + cc] + s0[512 + cc] + s0[768 + cc];
        sp += s0[128 + cc] + s0[384 + cc] + s0[640 + cc] + s0[896 + cc];
    }
    tot[c] += st;
    pos[c] += sp;
}

// ---------------- Kernel 3: row losses + per-class mean of means ----------------
__global__ __launch_bounds__(1024) void finalize_kernel(const float* __restrict__ pos,
                                                        const float* __restrict__ tot,
                                                        const int* __restrict__ lab,
                                                        float* __restrict__ out) {
    const int tid = threadIdx.x;
    float ls[NUM_CLASSES] = {0.f, 0.f, 0.f, 0.f};
    float lc[NUM_CLASSES] = {0.f, 0.f, 0.f, 0.f};
#pragma unroll
    for (int it = 0; it < N_PIX / 1024; ++it) {
        const int n = it * 1024 + tid;
        float rl = logf(tot[n] + 1e-6f) - logf(pos[n]);
        int c = lab[n];
#pragma unroll
        for (int k = 0; k < NUM_CLASSES; ++k) {
            if (c == k) {
                ls[k] += rl;
                lc[k] += 1.f;
            }
        }
    }
#pragma unroll
    for (int off = 1; off < 64; off <<= 1) {
#pragma unroll
        for (int k = 0; k < NUM_CLASSES; ++k) {
            ls[k] += __shfl_xor(ls[k], off, 64);
            lc[k] += __shfl_xor(lc[k], off, 64);
        }
    }
    __shared__ float ssum[16][NUM_CLASSES];
    __shared__ float scnt[16][NUM_CLASSES];
    const int wid = tid >> 6;
    if ((tid & 63) == 0) {
#pragma unroll
        for (int k = 0; k < NUM_CLASSES; ++k) {
            ssum[wid][k] = ls[k];
            scnt[wid][k] = lc[k];
        }
    }
    __syncthreads();
    if (tid == 0) {
        float acc = 0.f;
        int present = 0;
        for (int k = 0; k < NUM_CLASSES; ++k) {
            float s = 0.f, c = 0.f;
            for (int w = 0; w < 16; ++w) {
                s += ssum[w][k];
                c += scnt[w][k];
            }
            if (c > 0.f) {
                acc += s / c;
                present++;
            }
        }
        out[0] = acc / (float)(present > 0 ? present : 1);
    }
}

extern "C" void kernel_launch(void* const* d_in, const int* in_sizes, int n_in,
                              void* d_out, int out_size, void* d_ws, size_t ws_size,
                              hipStream_t stream) {
    const float* emb = (const float*)d_in[0];  // [2,128,64,64] fp32
    const int* lab = (const int*)d_in[1];      // [2,64,64] int32
    float* out = (float*)d_out;

    unsigned short* ebfT = (unsigned short*)d_ws;            // 2 MiB
    float* pos = (float*)((char*)d_ws + N_PIX * C_DIM * 2);  // [8192] f32
    float* tot = pos + N_PIX;                                // [8192] f32
    float* colscr = tot + N_PIX;                             // [2048 slots][4 waves][256] f32 = 8 MiB

    normscale_kernel<<<N_PIX / 16, 256, 0, stream>>>(emb, ebfT, pos);

    dim3 grid(64, 32);  // symmetric panel-pair cover
    pairwise_kernel<<<grid, 256, 0, stream>>>(ebfT, lab, pos, tot, colscr);

    colreduce_kernel<<<N_PIX / 256, 256, 0, stream>>>(colscr, pos, tot);

    finalize_kernel<<<1, 1024, 0, stream>>>(pos, tot, lab, out);
}

// Round 13
// 101.136 us; speedup vs baseline: 1.7452x; 1.4698x over previous
//
#include <hip/hip_runtime.h>
#include <hip/hip_bf16.h>

#define N_PIX 8192
#define C_DIM 128
#define HW 4096
// exp(dot/0.1) = exp2(dot * 14.42695...); fold sqrt of that into each vector.
#define PRESCALE 3.7982825f  // sqrt(log2(e)/0.1)
#define NUM_CLASSES 4

typedef __attribute__((ext_vector_type(8))) short short8;   // 8 x bf16 (4 VGPRs)
typedef __attribute__((ext_vector_type(4))) float float4v;  // 4 x f32 acc

// Fragment-linear layout (R7 win): ebfT[((T*4 + s)*64 + lane)*8 + j] = e[T*16 + lq][s*32 + quad*8 + j],
// lane = quad*16 + lq. Fragment load = base + lane*16B: one coalesced 1KB dwordx4.

// ---------------- Kernel 1: L2-normalize + prescale + bf16 cast into ebfT; zero pos/tot ----------------
__global__ __launch_bounds__(256) void normscale_kernel(const float* __restrict__ emb,
                                                        unsigned short* __restrict__ ebfT,
                                                        float* __restrict__ pz) {
    const int tid = threadIdx.x;
    const int p16 = tid & 15;   // pixel within tile (lq)
    const int g = tid >> 4;     // channel group 0..15 (8 channels each)
    const int n = blockIdx.x * 16 + p16;
    const int b = n >> 12;
    const int hw = n & (HW - 1);
    const float* base = emb + b * (C_DIM * HW) + hw;

    float v[8];
    float ss = 0.f;
#pragma unroll
    for (int i = 0; i < 8; ++i) {
        v[i] = base[(g * 8 + i) * HW];
        ss += v[i] * v[i];
    }
    ss += __shfl_xor(ss, 16, 64);
    ss += __shfl_xor(ss, 32, 64);
    __shared__ float red[4][16];
    const int wv = tid >> 6;
    if ((tid & 63) < 16) red[wv][p16] = ss;
    __syncthreads();
    float tot = red[0][p16] + red[1][p16] + red[2][p16] + red[3][p16];
    float inv = PRESCALE / fmaxf(sqrtf(tot), 1e-12f);

    unsigned short us[8];
#pragma unroll
    for (int i = 0; i < 8; ++i) {
        __hip_bfloat16 h = __float2bfloat16(v[i] * inv);
        us[i] = *reinterpret_cast<unsigned short*>(&h);
    }
    const int s = g >> 2, quad = g & 3;
    unsigned short* dst = ebfT + (((blockIdx.x * 4 + s) * 64 + quad * 16 + p16) << 3);
    *reinterpret_cast<short8*>(dst) = *reinterpret_cast<short8*>(us);

    if (blockIdx.x < 64) pz[blockIdx.x * 256 + tid] = 0.f;
}

// ---------------- Kernel 2: symmetric fused S = e e^T, exp2, row+col sums ----------------
// Grid (64, 32): bi = I-panel (128 rows), d = blockIdx.y+1 in 1..32; jp = (bi+d)%64.
// d=1..31 covers each unordered off-diag panel pair once; d=32 double-covers -> bi>=32 culled.
// Phase 1 (all blocks): off-diag pair, single path, no masking. Col-side partials are
//   quad-reduced per tile and written via plain global stores to a (slot, wave)-private
//   scratch region; colreduce_kernel sums the slots afterwards. NO LDS in this kernel.
// Phase 2 (d==1 only): diagonal panel, separate sequential loop, self-mask, row-side only.
// HARD-WON toolchain rules:
//   *** NEVER `#pragma unroll` the MFMA tile loop *** — full unroll hoists all B-tile
//   dwordx4 loads (8 tiles x 16 VGPRs) -> forced spill. This, not LDS/atomics/arrays,
//   is the R6/R10/R11/R12 demotion signature (VGPR 64, FETCH+WRITE >100MB). Clean
//   rounds R4/R7/R9 all had rolled tile loops.
//   R3: (256,8) caps VGPR at 64 -> spill; keep (256,4).
//   R5: global_load_lds on cache-resident input explodes HBM traffic -> plain loads.
//   R6: no lambdas; constant-indexed arrays only.
//   R9: in-loop global ATOMIC flush = 2.1M L2 RMWs (~15-20us) -> plain stores instead.
__global__ __launch_bounds__(256, 4) void pairwise_kernel(const unsigned short* __restrict__ ebfT,
                                                          const int* __restrict__ lab,
                                                          float* __restrict__ pos,
                                                          float* __restrict__ tot,
                                                          float* __restrict__ colscr) {
    const int bi = blockIdx.x;
    const int d = blockIdx.y + 1;          // 1..32
    if (d == 32 && bi >= 32) return;       // wrap double-cover cull (block-uniform)
    const int jp = (bi + d) & 63;
    const int Ipanel = bi << 7;
    const int Jpanel = jp << 7;

    const int wave = threadIdx.x >> 6;
    const int lane = threadIdx.x & 63;
    const int quad = lane >> 4;
    const int lq = lane & 15;

    const int I0 = Ipanel + wave * 32;
    // (slot, wave)-private scratch: colscr[((sid*4 + wave)*256) + {0|128} + col]
    float* scrw = colscr + (((((d - 1) << 6) + bi) << 2) + wave) * 256;

    // A fragments: tiles (I0>>4), (I0>>4)+1 — coalesced lane*16B loads.
    short8 afrag[2][4];
#pragma unroll
    for (int a = 0; a < 2; ++a) {
        const unsigned short* ab = ebfT + ((((I0 >> 4) + a) * 4) * 64 + lane) * 8;
#pragma unroll
        for (int s = 0; s < 4; ++s)
            afrag[a][s] = *reinterpret_cast<const short8*>(ab + s * 512);
    }
    int lab_row[2][4];
#pragma unroll
    for (int a = 0; a < 2; ++a)
#pragma unroll
        for (int r = 0; r < 4; ++r) lab_row[a][r] = lab[I0 + a * 16 + quad * 4 + r];

    float tacc[2][4] = {};
    float pacc[2][4] = {};

    // ---- Phase 1: off-diagonal panel pair (no masking, row + col side) ----
    // NOTE: tile loop deliberately NOT unrolled (see toolchain rules above).
    {
        const unsigned short* bbase = ebfT + ((Jpanel >> 4) * 4 * 64 + lane) * 8;
        for (int t = 0; t < 8; ++t) {
            const int lab_col = lab[Jpanel + t * 16 + lq];
            const unsigned short* bt = bbase + t * 2048;
            short8 bfrag[4];
#pragma unroll
            for (int s = 0; s < 4; ++s)
                bfrag[s] = *reinterpret_cast<const short8*>(bt + s * 512);

            float4v acc0 = {0.f, 0.f, 0.f, 0.f};
            float4v acc1 = {0.f, 0.f, 0.f, 0.f};
#pragma unroll
            for (int s = 0; s < 4; ++s) {
                acc0 = __builtin_amdgcn_mfma_f32_16x16x32_bf16(afrag[0][s], bfrag[s], acc0, 0, 0, 0);
                acc1 = __builtin_amdgcn_mfma_f32_16x16x32_bf16(afrag[1][s], bfrag[s], acc1, 0, 0, 0);
            }

            float colTs = 0.f, colPs = 0.f;
#pragma unroll
            for (int r = 0; r < 4; ++r) {
                float ex = __builtin_amdgcn_exp2f(acc0[r]);
                tacc[0][r] += ex;
                float pxe = (lab_row[0][r] == lab_col) ? ex : 0.f;
                pacc[0][r] += pxe;
                colTs += ex;
                colPs += pxe;
            }
#pragma unroll
            for (int r = 0; r < 4; ++r) {
                float ex = __builtin_amdgcn_exp2f(acc1[r]);
                tacc[1][r] += ex;
                float pxe = (lab_row[1][r] == lab_col) ? ex : 0.f;
                pacc[1][r] += pxe;
                colTs += ex;
                colPs += pxe;
            }
            // col-side: reduce over quads; quad 0 stores the wave's 32-row partial.
            colTs += __shfl_xor(colTs, 16, 64);
            colTs += __shfl_xor(colTs, 32, 64);
            colPs += __shfl_xor(colPs, 16, 64);
            colPs += __shfl_xor(colPs, 32, 64);
            if (quad == 0) {
                scrw[t * 16 + lq] = colTs;
                scrw[128 + t * 16 + lq] = colPs;
            }
        }
    }

    // ---- Phase 2 (d==1 blocks only): diagonal panel bi, self-masked, row-side only ----
#define EPILOGUE(A, ACC, MASKED)                                            \
    {                                                                       \
        _Pragma("unroll") for (int r = 0; r < 4; ++r) {                     \
            float ex = __builtin_amdgcn_exp2f(ACC[r]);                      \
            if (MASKED) ex = (lq == quad * 4 + r) ? 0.f : ex;               \
            tacc[A][r] += ex;                                               \
            pacc[A][r] += (lab_row[A][r] == lab_col) ? ex : 0.f;            \
        }                                                                   \
    }
    if (d == 1) {
        const unsigned short* bbase = ebfT + ((Ipanel >> 4) * 4 * 64 + lane) * 8;
        for (int t = 0; t < 8; ++t) {
            const int J = Ipanel + t * 16;
            const int lab_col = lab[J + lq];
            const unsigned short* bt = bbase + t * 2048;
            short8 bfrag[4];
#pragma unroll
            for (int s = 0; s < 4; ++s)
                bfrag[s] = *reinterpret_cast<const short8*>(bt + s * 512);

            float4v acc0 = {0.f, 0.f, 0.f, 0.f};
            float4v acc1 = {0.f, 0.f, 0.f, 0.f};
#pragma unroll
            for (int s = 0; s < 4; ++s) {
                acc0 = __builtin_amdgcn_mfma_f32_16x16x32_bf16(afrag[0][s], bfrag[s], acc0, 0, 0, 0);
                acc1 = __builtin_amdgcn_mfma_f32_16x16x32_bf16(afrag[1][s], bfrag[s], acc1, 0, 0, 0);
            }
            if (J == I0) EPILOGUE(0, acc0, true) else EPILOGUE(0, acc0, false);
            if (J == I0 + 16) EPILOGUE(1, acc1, true) else EPILOGUE(1, acc1, false);
        }
    }
#undef EPILOGUE

    // ---- Row-side flush (covers phase 1 + phase 2): one atomic per row per block ----
#pragma unroll
    for (int a = 0; a < 2; ++a) {
#pragma unroll
        for (int r = 0; r < 4; ++r) {
            float t = tacc[a][r], p = pacc[a][r];
#pragma unroll
            for (int off = 1; off < 16; off <<= 1) {
                t += __shfl_xor(t, off, 64);
                p += __shfl_xor(p, off, 64);
            }
            if (lq == 0) {
                const int row = I0 + a * 16 + quad * 4 + r;
                atomicAdd(&tot[row], t);
                atomicAdd(&pos[row], p);
            }
        }
    }
}

// ---------------- Kernel 2b: col-side reduce of scratch slots into tot/pos ----------------
// One thread per col c. Sums the 4 wave-quarters of every valid slot (bi=(jp-d)%64, d).
__global__ __launch_bounds__(256) void colreduce_kernel(const float* __restrict__ colscr,
                                                        float* __restrict__ pos,
                                                        float* __restrict__ tot) {
    const int c = blockIdx.x * 256 + threadIdx.x;  // 0..8191
    const int jpp = c >> 7;
    const int cc = c & 127;
    float st = 0.f, sp = 0.f;
    for (int d = 1; d <= 32; ++d) {
        const int bi = (jpp - d + 64) & 63;
        if (d == 32 && bi >= 32) continue;
        const float* s0 = colscr + ((((d - 1) << 6) + bi) << 2) * 256;
        st += s0[cc] + s0[256 + cc] + s0[512 + cc] + s0[768 + cc];
        sp += s0[128 + cc] + s0[384 + cc] + s0[640 + cc] + s0[896 + cc];
    }
    tot[c] += st;
    pos[c] += sp;
}

// ---------------- Kernel 3: row losses + per-class mean of means ----------------
__global__ __launch_bounds__(1024) void finalize_kernel(const float* __restrict__ pos,
                                                        const float* __restrict__ tot,
                                                        const int* __restrict__ lab,
                                                        float* __restrict__ out) {
    const int tid = threadIdx.x;
    float ls[NUM_CLASSES] = {0.f, 0.f, 0.f, 0.f};
    float lc[NUM_CLASSES] = {0.f, 0.f, 0.f, 0.f};
#pragma unroll
    for (int it = 0; it < N_PIX / 1024; ++it) {
        const int n = it * 1024 + tid;
        float rl = logf(tot[n] + 1e-6f) - logf(pos[n]);
        int c = lab[n];
#pragma unroll
        for (int k = 0; k < NUM_CLASSES; ++k) {
            if (c == k) {
                ls[k] += rl;
                lc[k] += 1.f;
            }
        }
    }
#pragma unroll
    for (int off = 1; off < 64; off <<= 1) {
#pragma unroll
        for (int k = 0; k < NUM_CLASSES; ++k) {
            ls[k] += __shfl_xor(ls[k], off, 64);
            lc[k] += __shfl_xor(lc[k], off, 64);
        }
    }
    __shared__ float ssum[16][NUM_CLASSES];
    __shared__ float scnt[16][NUM_CLASSES];
    const int wid = tid >> 6;
    if ((tid & 63) == 0) {
#pragma unroll
        for (int k = 0; k < NUM_CLASSES; ++k) {
            ssum[wid][k] = ls[k];
            scnt[wid][k] = lc[k];
        }
    }
    __syncthreads();
    if (tid == 0) {
        float acc = 0.f;
        int present = 0;
        for (int k = 0; k < NUM_CLASSES; ++k) {
            float s = 0.f, c = 0.f;
            for (int w = 0; w < 16; ++w) {
                s += ssum[w][k];
                c += scnt[w][k];
            }
            if (c > 0.f) {
                acc += s / c;
                present++;
            }
        }
        out[0] = acc / (float)(present > 0 ? present : 1);
    }
}

extern "C" void kernel_launch(void* const* d_in, const int* in_sizes, int n_in,
                              void* d_out, int out_size, void* d_ws, size_t ws_size,
                              hipStream_t stream) {
    const float* emb = (const float*)d_in[0];  // [2,128,64,64] fp32
    const int* lab = (const int*)d_in[1];      // [2,64,64] int32
    float* out = (float*)d_out;

    unsigned short* ebfT = (unsigned short*)d_ws;            // 2 MiB
    float* pos = (float*)((char*)d_ws + N_PIX * C_DIM * 2);  // [8192] f32
    float* tot = pos + N_PIX;                                // [8192] f32
    float* colscr = tot + N_PIX;                             // [2048 slots][4 waves][256] f32 = 8 MiB

    normscale_kernel<<<N_PIX / 16, 256, 0, stream>>>(emb, ebfT, pos);

    dim3 grid(64, 32);  // symmetric panel-pair cover
    pairwise_kernel<<<grid, 256, 0, stream>>>(ebfT, lab, pos, tot, colscr);

    colreduce_kernel<<<N_PIX / 256, 256, 0, stream>>>(colscr, pos, tot);

    finalize_kernel<<<1, 1024, 0, stream>>>(pos, tot, lab, out);
}

// Round 14
// 95.199 us; speedup vs baseline: 1.8541x; 1.0624x over previous
//
#include <hip/hip_runtime.h>
#include <hip/hip_bf16.h>

#define N_PIX 8192
#define C_DIM 128
#define HW 4096
// exp(dot/0.1) = exp2(dot * 14.42695...); fold sqrt of that into each vector.
#define PRESCALE 3.7982825f  // sqrt(log2(e)/0.1)
#define NUM_CLASSES 4

typedef __attribute__((ext_vector_type(8))) short short8;   // 8 x bf16 (4 VGPRs)
typedef __attribute__((ext_vector_type(4))) float float4v;  // 4 x f32 acc

// Fragment-linear layout (R7 win): ebfT[((T*4 + s)*64 + lane)*8 + j] = e[T*16 + lq][s*32 + quad*8 + j],
// lane = quad*16 + lq. Fragment load = base + lane*16B: one coalesced 1KB dwordx4.

// ---------------- Kernel 1: L2-normalize + prescale + bf16 cast into ebfT; zero pos/tot ----------------
__global__ __launch_bounds__(256) void normscale_kernel(const float* __restrict__ emb,
                                                        unsigned short* __restrict__ ebfT,
                                                        float* __restrict__ pz) {
    const int tid = threadIdx.x;
    const int p16 = tid & 15;   // pixel within tile (lq)
    const int g = tid >> 4;     // channel group 0..15 (8 channels each)
    const int n = blockIdx.x * 16 + p16;
    const int b = n >> 12;
    const int hw = n & (HW - 1);
    const float* base = emb + b * (C_DIM * HW) + hw;

    float v[8];
    float ss = 0.f;
#pragma unroll
    for (int i = 0; i < 8; ++i) {
        v[i] = base[(g * 8 + i) * HW];
        ss += v[i] * v[i];
    }
    ss += __shfl_xor(ss, 16, 64);
    ss += __shfl_xor(ss, 32, 64);
    __shared__ float red[4][16];
    const int wv = tid >> 6;
    if ((tid & 63) < 16) red[wv][p16] = ss;
    __syncthreads();
    float tot = red[0][p16] + red[1][p16] + red[2][p16] + red[3][p16];
    float inv = PRESCALE / fmaxf(sqrtf(tot), 1e-12f);

    unsigned short us[8];
#pragma unroll
    for (int i = 0; i < 8; ++i) {
        __hip_bfloat16 h = __float2bfloat16(v[i] * inv);
        us[i] = *reinterpret_cast<unsigned short*>(&h);
    }
    const int s = g >> 2, quad = g & 3;
    unsigned short* dst = ebfT + (((blockIdx.x * 4 + s) * 64 + quad * 16 + p16) << 3);
    *reinterpret_cast<short8*>(dst) = *reinterpret_cast<short8*>(us);

    if (blockIdx.x < 64) pz[blockIdx.x * 256 + tid] = 0.f;
}

// ---------------- Kernel 2: symmetric fused S = e e^T, exp2, row+col sums ----------------
// Grid (64, 32): bi = I-panel (128 rows), d = blockIdx.y+1 in 1..32; jp = (bi+d)%64.
// d=1..31 covers each unordered off-diag panel pair once; d=32 double-covers -> bi>=32 culled.
// Phase 1 (all blocks): off-diag pair, single path, no masking. Col-side partials are
//   quad-reduced per tile and flushed with fire-and-forget global atomicAdd (no return
//   value -> no dependent waitcnt -> doesn't stall the wave; R13 proved the
//   store+reduce alternative is 6us WORSE due to the extra kernel + scratch traffic).
// Phase 2 (d==1 only): diagonal panel, separate sequential loop, self-mask, row-side only.
// HARD-WON toolchain rules:
//   *** NEVER fully `#pragma unroll` the MFMA tile loop *** — hoists all B-tile loads
//   -> forced spill (VGPR 64 + FETCH/WRITE >100MB signature; R6/R10/R11/R12).
//   `#pragma unroll 2` (this round's single change vs R9) keeps only 2 tiles in
//   flight (~+16 VGPRs) for load/compute overlap.
//   R3: (256,8) caps VGPR -> spill; keep (256,4).
//   R5: global_load_lds on cache-resident input explodes HBM traffic -> plain loads.
//   R6: no lambdas; constant-indexed arrays only.
__global__ __launch_bounds__(256, 4) void pairwise_kernel(const unsigned short* __restrict__ ebfT,
                                                          const int* __restrict__ lab,
                                                          float* __restrict__ pos,
                                                          float* __restrict__ tot) {
    const int bi = blockIdx.x;
    const int d = blockIdx.y + 1;          // 1..32
    if (d == 32 && bi >= 32) return;       // wrap double-cover cull (block-uniform)
    const int jp = (bi + d) & 63;
    const int Ipanel = bi << 7;
    const int Jpanel = jp << 7;

    const int wave = threadIdx.x >> 6;
    const int lane = threadIdx.x & 63;
    const int quad = lane >> 4;
    const int lq = lane & 15;

    const int I0 = Ipanel + wave * 32;

    // A fragments: tiles (I0>>4), (I0>>4)+1 — coalesced lane*16B loads.
    short8 afrag[2][4];
#pragma unroll
    for (int a = 0; a < 2; ++a) {
        const unsigned short* ab = ebfT + ((((I0 >> 4) + a) * 4) * 64 + lane) * 8;
#pragma unroll
        for (int s = 0; s < 4; ++s)
            afrag[a][s] = *reinterpret_cast<const short8*>(ab + s * 512);
    }
    int lab_row[2][4];
#pragma unroll
    for (int a = 0; a < 2; ++a)
#pragma unroll
        for (int r = 0; r < 4; ++r) lab_row[a][r] = lab[I0 + a * 16 + quad * 4 + r];

    float tacc[2][4] = {};
    float pacc[2][4] = {};

    // ---- Phase 1: off-diagonal panel pair (no masking, row + col side) ----
    {
        const unsigned short* bbase = ebfT + ((Jpanel >> 4) * 4 * 64 + lane) * 8;
#pragma unroll 2
        for (int t = 0; t < 8; ++t) {
            const int lab_col = lab[Jpanel + t * 16 + lq];
            const unsigned short* bt = bbase + t * 2048;
            short8 bfrag[4];
#pragma unroll
            for (int s = 0; s < 4; ++s)
                bfrag[s] = *reinterpret_cast<const short8*>(bt + s * 512);

            float4v acc0 = {0.f, 0.f, 0.f, 0.f};
            float4v acc1 = {0.f, 0.f, 0.f, 0.f};
#pragma unroll
            for (int s = 0; s < 4; ++s) {
                acc0 = __builtin_amdgcn_mfma_f32_16x16x32_bf16(afrag[0][s], bfrag[s], acc0, 0, 0, 0);
                acc1 = __builtin_amdgcn_mfma_f32_16x16x32_bf16(afrag[1][s], bfrag[s], acc1, 0, 0, 0);
            }

            float colTs = 0.f, colPs = 0.f;
#pragma unroll
            for (int r = 0; r < 4; ++r) {
                float ex = __builtin_amdgcn_exp2f(acc0[r]);
                tacc[0][r] += ex;
                float pxe = (lab_row[0][r] == lab_col) ? ex : 0.f;
                pacc[0][r] += pxe;
                colTs += ex;
                colPs += pxe;
            }
#pragma unroll
            for (int r = 0; r < 4; ++r) {
                float ex = __builtin_amdgcn_exp2f(acc1[r]);
                tacc[1][r] += ex;
                float pxe = (lab_row[1][r] == lab_col) ? ex : 0.f;
                pacc[1][r] += pxe;
                colTs += ex;
                colPs += pxe;
            }
            // col-side: reduce over quads; quad 0 issues fire-and-forget atomics.
            colTs += __shfl_xor(colTs, 16, 64);
            colTs += __shfl_xor(colTs, 32, 64);
            colPs += __shfl_xor(colPs, 16, 64);
            colPs += __shfl_xor(colPs, 32, 64);
            if (quad == 0) {
                atomicAdd(&tot[Jpanel + t * 16 + lq], colTs);
                atomicAdd(&pos[Jpanel + t * 16 + lq], colPs);
            }
        }
    }

    // ---- Phase 2 (d==1 blocks only): diagonal panel bi, self-masked, row-side only ----
#define EPILOGUE(A, ACC, MASKED)                                            \
    {                                                                       \
        _Pragma("unroll") for (int r = 0; r < 4; ++r) {                     \
            float ex = __builtin_amdgcn_exp2f(ACC[r]);                      \
            if (MASKED) ex = (lq == quad * 4 + r) ? 0.f : ex;               \
            tacc[A][r] += ex;                                               \
            pacc[A][r] += (lab_row[A][r] == lab_col) ? ex : 0.f;            \
        }                                                                   \
    }
    if (d == 1) {
        const unsigned short* bbase = ebfT + ((Ipanel >> 4) * 4 * 64 + lane) * 8;
        for (int t = 0; t < 8; ++t) {
            const int J = Ipanel + t * 16;
            const int lab_col = lab[J + lq];
            const unsigned short* bt = bbase + t * 2048;
            short8 bfrag[4];
#pragma unroll
            for (int s = 0; s < 4; ++s)
                bfrag[s] = *reinterpret_cast<const short8*>(bt + s * 512);

            float4v acc0 = {0.f, 0.f, 0.f, 0.f};
            float4v acc1 = {0.f, 0.f, 0.f, 0.f};
#pragma unroll
            for (int s = 0; s < 4; ++s) {
                acc0 = __builtin_amdgcn_mfma_f32_16x16x32_bf16(afrag[0][s], bfrag[s], acc0, 0, 0, 0);
                acc1 = __builtin_amdgcn_mfma_f32_16x16x32_bf16(afrag[1][s], bfrag[s], acc1, 0, 0, 0);
            }
            if (J == I0) EPILOGUE(0, acc0, true) else EPILOGUE(0, acc0, false);
            if (J == I0 + 16) EPILOGUE(1, acc1, true) else EPILOGUE(1, acc1, false);
        }
    }
#undef EPILOGUE

    // ---- Row-side flush (covers phase 1 + phase 2): one atomic per row per block ----
#pragma unroll
    for (int a = 0; a < 2; ++a) {
#pragma unroll
        for (int r = 0; r < 4; ++r) {
            float t = tacc[a][r], p = pacc[a][r];
#pragma unroll
            for (int off = 1; off < 16; off <<= 1) {
                t += __shfl_xor(t, off, 64);
                p += __shfl_xor(p, off, 64);
            }
            if (lq == 0) {
                const int row = I0 + a * 16 + quad * 4 + r;
                atomicAdd(&tot[row], t);
                atomicAdd(&pos[row], p);
            }
        }
    }
}

// ---------------- Kernel 3: row losses + per-class mean of means ----------------
__global__ __launch_bounds__(1024) void finalize_kernel(const float* __restrict__ pos,
                                                        const float* __restrict__ tot,
                                                        const int* __restrict__ lab,
                                                        float* __restrict__ out) {
    const int tid = threadIdx.x;
    float ls[NUM_CLASSES] = {0.f, 0.f, 0.f, 0.f};
    float lc[NUM_CLASSES] = {0.f, 0.f, 0.f, 0.f};
#pragma unroll
    for (int it = 0; it < N_PIX / 1024; ++it) {
        const int n = it * 1024 + tid;
        float rl = logf(tot[n] + 1e-6f) - logf(pos[n]);
        int c = lab[n];
#pragma unroll
        for (int k = 0; k < NUM_CLASSES; ++k) {
            if (c == k) {
                ls[k] += rl;
                lc[k] += 1.f;
            }
        }
    }
#pragma unroll
    for (int off = 1; off < 64; off <<= 1) {
#pragma unroll
        for (int k = 0; k < NUM_CLASSES; ++k) {
            ls[k] += __shfl_xor(ls[k], off, 64);
            lc[k] += __shfl_xor(lc[k], off, 64);
        }
    }
    __shared__ float ssum[16][NUM_CLASSES];
    __shared__ float scnt[16][NUM_CLASSES];
    const int wid = tid >> 6;
    if ((tid & 63) == 0) {
#pragma unroll
        for (int k = 0; k < NUM_CLASSES; ++k) {
            ssum[wid][k] = ls[k];
            scnt[wid][k] = lc[k];
        }
    }
    __syncthreads();
    if (tid == 0) {
        float acc = 0.f;
        int present = 0;
        for (int k = 0; k < NUM_CLASSES; ++k) {
            float s = 0.f, c = 0.f;
            for (int w = 0; w < 16; ++w) {
                s += ssum[w][k];
                c += scnt[w][k];
            }
            if (c > 0.f) {
                acc += s / c;
                present++;
            }
        }
        out[0] = acc / (float)(present > 0 ? present : 1);
    }
}

extern "C" void kernel_launch(void* const* d_in, const int* in_sizes, int n_in,
                              void* d_out, int out_size, void* d_ws, size_t ws_size,
                              hipStream_t stream) {
    const float* emb = (const float*)d_in[0];  // [2,128,64,64] fp32
    const int* lab = (const int*)d_in[1];      // [2,64,64] int32
    float* out = (float*)d_out;

    unsigned short* ebfT = (unsigned short*)d_ws;            // 2 MiB
    float* pos = (float*)((char*)d_ws + N_PIX * C_DIM * 2);  // [8192] f32
    float* tot = pos + N_PIX;                                // [8192] f32 (contiguous)

    normscale_kernel<<<N_PIX / 16, 256, 0, stream>>>(emb, ebfT, pos);

    dim3 grid(64, 32);  // symmetric panel-pair cover
    pairwise_kernel<<<grid, 256, 0, stream>>>(ebfT, lab, pos, tot);

    finalize_kernel<<<1, 1024, 0, stream>>>(pos, tot, lab, out);
}